// Round 6
// baseline (11512.403 us; speedup 1.0000x reference)
//
#include <hip/hip_runtime.h>

// ============================================================================
// RSSM (DynamicsModel) on MI355X — round 6.
// Diagnosis r5: K-loop latency already hidden (3-deep neutral); per-step cost
// is ~11us PER DISPATCH x 7.  Fix: 7 -> 4 launches/step via fusion:
//   1. sa GEMM (proven)
//   2. gigh_gru: gi+gh GEMMs (gate-permuted weights, 128x96 tile, dual
//      accumulators) + full GRU epilogue -> writes h directly
//   3. ha/ho un-split GEMM w/ fused Ci+ReLU+bf16 epilogue (proven template)
//   4. prior/post GEMM w/ fused rsample epilogue (round-3-verified layout)
// GEMM core: 128-tile, BK=64, 2-deep dbuf, XOR-swizzle, counted vmcnt.
// ============================================================================

typedef __attribute__((ext_vector_type(8))) short bf16x8;
typedef __attribute__((ext_vector_type(4))) float f32x4;
typedef __attribute__((ext_vector_type(4))) short s16x4;

#define DEVI static __device__ __forceinline__

DEVI float bf2f(short s) { union { float f; unsigned u; } v; v.u = ((unsigned)(unsigned short)s) << 16; return v.f; }
DEVI short f2bf(float f) {
  union { float f; unsigned u; } v; v.f = f;
  unsigned r = v.u + 0x7FFFu + ((v.u >> 16) & 1u);   // RNE
  return (short)(r >> 16);
}

#define Bsz 256
#define Tsz 64
#define Hsz 2048
#define Ssz 512
#define Asz 64
#define Esz 2048
#define TM1 63

#define OUT_PS  33554432L
#define OUT_QS  41943040L
#define OUT_PM  50331648L
#define OUT_PLV 58589184L
#define OUT_QM  66846720L
#define OUT_QLV 75104256L

struct GArg {
  const short* A; const short* Bt; const float* bias; const short* Ci;
  float* oF; short* oB;
  int lda, ldb, ldoF, ldoB; long ldci, pstride;
};

// ---------------------------------------------------------------------------
// generic bf16 GEMM: 128x128 tile, BK=64, 2-deep dbuf, swizzled LDS,
// counted vmcnt(8).  blockIdx.z: gemm = z&1, kc = z>>1 (split-K chunk).
// ---------------------------------------------------------------------------
template<int HASBIAS, int HASCI, int RELU, int OUTF, int OUTB>
__global__ __launch_bounds__(256) void gemm_bt(GArg g0, GArg g1, int kcK) {
  const int gemm = blockIdx.z & 1, kc = blockIdx.z >> 1;
  const GArg g = gemm ? g1 : g0;
  const short* __restrict__ Ag = g.A + (long)kc * kcK;
  const short* __restrict__ Bg = g.Bt + (long)kc * kcK;
  __shared__ __align__(16) short As[2][8192];
  __shared__ __align__(16) short Bs[2][8192];
  const int tid = threadIdx.x;
  const int w = tid >> 6, l = tid & 63;
  const int bm0 = blockIdx.y << 7, bn0 = blockIdx.x << 7;
  const int fc = l & 15, fh = l >> 4;
  const int wr = (w >> 1) << 6, wc = (w & 1) << 6;
  const int rx = fc & 7;

  const int srccol = ((l & 7) ^ ((l >> 3) & 7)) << 3;
  long aoff[4], boff[4];
#pragma unroll
  for (int i = 0; i < 4; ++i) {
    const int row = (((i << 2) + w) << 3) + (l >> 3);
    aoff[i] = (long)(bm0 + row) * g.lda + srccol;
    boff[i] = (long)(bn0 + row) * g.ldb + srccol;
  }

  f32x4 acc[4][4];
#pragma unroll
  for (int i = 0; i < 4; ++i)
#pragma unroll
    for (int j = 0; j < 4; ++j) acc[i][j] = f32x4{0.f, 0.f, 0.f, 0.f};

  auto STAGE = [&](int kt, int buf) {
#pragma unroll
    for (int i = 0; i < 4; ++i) {
      const int ib = ((i << 2) + w) << 10;
      __builtin_amdgcn_global_load_lds(
          (const __attribute__((address_space(1))) void*)(Ag + aoff[i] + (kt << 6)),
          (__attribute__((address_space(3))) void*)((char*)&As[buf][0] + ib), 16, 0, 0);
      __builtin_amdgcn_global_load_lds(
          (const __attribute__((address_space(1))) void*)(Bg + boff[i] + (kt << 6)),
          (__attribute__((address_space(3))) void*)((char*)&Bs[buf][0] + ib), 16, 0, 0);
    }
  };
  auto COMPUTE = [&](int buf) {
#pragma unroll
    for (int kk = 0; kk < 2; ++kk) {
      bf16x8 af[4], bb[4];
#pragma unroll
      for (int mi = 0; mi < 4; ++mi)
        af[mi] = *(const bf16x8*)&As[buf][(wr + (mi << 4) + fc) * 64 + ((((kk << 2) + fh) ^ rx) << 3)];
#pragma unroll
      for (int ni = 0; ni < 4; ++ni)
        bb[ni] = *(const bf16x8*)&Bs[buf][(wc + (ni << 4) + fc) * 64 + ((((kk << 2) + fh) ^ rx) << 3)];
#pragma unroll
      for (int mi = 0; mi < 4; ++mi)
#pragma unroll
        for (int ni = 0; ni < 4; ++ni)
          acc[mi][ni] = __builtin_amdgcn_mfma_f32_16x16x32_bf16(af[mi], bb[ni], acc[mi][ni], 0, 0, 0);
    }
  };

  const int nk = kcK >> 6;
  STAGE(0, 0);
  for (int kt = 0; kt < nk - 1; ++kt) {
    STAGE(kt + 1, (kt + 1) & 1);
    asm volatile("s_waitcnt vmcnt(8)" ::: "memory");
    __builtin_amdgcn_s_barrier();
    __builtin_amdgcn_sched_barrier(0);
    COMPUTE(kt & 1);
    asm volatile("s_waitcnt lgkmcnt(0)" ::: "memory");
    __builtin_amdgcn_s_barrier();
  }
  asm volatile("s_waitcnt vmcnt(0)" ::: "memory");
  __builtin_amdgcn_s_barrier();
  __builtin_amdgcn_sched_barrier(0);
  COMPUTE((nk - 1) & 1);

  float* oF = OUTF ? (g.oF + (long)kc * g.pstride) : (float*)nullptr;
#pragma unroll
  for (int mi = 0; mi < 4; ++mi) {
#pragma unroll
    for (int ni = 0; ni < 4; ++ni) {
      const int n = bn0 + wc + (ni << 4) + fc;
      float bv = 0.f;
      if (HASBIAS) bv = g.bias[n];
#pragma unroll
      for (int r = 0; r < 4; ++r) {
        const int m = bm0 + wr + (mi << 4) + (fh << 2) + r;
        float v = acc[mi][ni][r] + bv;
        if (HASCI) v += bf2f(g.Ci[(long)m * g.ldci + n]);
        if (RELU) v = fmaxf(v, 0.f);
        if (OUTF) oF[(long)m * g.ldoF + n] = v;
        if (OUTB) g.oB[(long)m * g.ldoB + n] = f2bf(v);
      }
    }
  }
}

// ---------------------------------------------------------------------------
// gi+gh+GRU fused.  Weights gate-permuted: row' = (j>>4)*48 + g*16 + (j&15)
// (orig row = g*2048 + j).  Block tile 128x96; wave = 64x48 (4mi x 3ni); two
// accumulator sets (gi: sa@Wih', gh: h@Whh').  Epilogue: full GRU update,
// writes h fp32 (out) + bf16 (h_b).  Grid dim3(64, 2, 1).
// ---------------------------------------------------------------------------
__global__ __launch_bounds__(256) void gigh_gru(
    const short* __restrict__ sa, const short* __restrict__ hprev_b,
    const short* __restrict__ Wih, const short* __restrict__ Whh,
    const float* __restrict__ b_ih, const float* __restrict__ b_hh,
    const float* __restrict__ hold, float* __restrict__ hnew,
    short* __restrict__ hb) {
  __shared__ __align__(16) short AsS[2][8192];
  __shared__ __align__(16) short AsH[2][8192];
  __shared__ __align__(16) short BsI[2][6144];
  __shared__ __align__(16) short BsH[2][6144];
  const int tid = threadIdx.x;
  const int w = tid >> 6, l = tid & 63;
  const int bm0 = blockIdx.y << 7;
  const int bn0 = blockIdx.x * 96;
  const int fc = l & 15, fh = l >> 4;
  const int wr = (w >> 1) << 6;
  const int wn = (w & 1) * 48;
  const int rx = fc & 7;
  const int srccol = ((l & 7) ^ ((l >> 3) & 7)) << 3;

  long aoffS[4], aoffH[4], boffI[3], boffH[3];
#pragma unroll
  for (int i = 0; i < 4; ++i) {
    const int row = (((i << 2) + w) << 3) + (l >> 3);
    aoffS[i] = (long)(bm0 + row) * Hsz + srccol;
    aoffH[i] = aoffS[i];
  }
#pragma unroll
  for (int i = 0; i < 3; ++i) {
    const int row = (((i << 2) + w) << 3) + (l >> 3);       // 0..95
    boffI[i] = (long)(bn0 + row) * Hsz + srccol;
    boffH[i] = boffI[i];
  }

  f32x4 acc_i[4][3], acc_h[4][3];
#pragma unroll
  for (int i = 0; i < 4; ++i)
#pragma unroll
    for (int j = 0; j < 3; ++j) { acc_i[i][j] = f32x4{0.f,0.f,0.f,0.f}; acc_h[i][j] = f32x4{0.f,0.f,0.f,0.f}; }

  auto STAGE = [&](int kt, int buf) {
#pragma unroll
    for (int i = 0; i < 4; ++i) {
      const int ib = ((i << 2) + w) << 10;
      __builtin_amdgcn_global_load_lds(
          (const __attribute__((address_space(1))) void*)(sa + aoffS[i] + (kt << 6)),
          (__attribute__((address_space(3))) void*)((char*)&AsS[0][0] + (buf << 14) + ib), 16, 0, 0);
      __builtin_amdgcn_global_load_lds(
          (const __attribute__((address_space(1))) void*)(hprev_b + aoffH[i] + (kt << 6)),
          (__attribute__((address_space(3))) void*)((char*)&AsH[0][0] + (buf << 14) + ib), 16, 0, 0);
    }
#pragma unroll
    for (int i = 0; i < 3; ++i) {
      const int ib = ((i << 2) + w) << 10;
      __builtin_amdgcn_global_load_lds(
          (const __attribute__((address_space(1))) void*)(Wih + boffI[i] + (kt << 6)),
          (__attribute__((address_space(3))) void*)((char*)&BsI[0][0] + buf * 12288 + ib), 16, 0, 0);
      __builtin_amdgcn_global_load_lds(
          (const __attribute__((address_space(1))) void*)(Whh + boffH[i] + (kt << 6)),
          (__attribute__((address_space(3))) void*)((char*)&BsH[0][0] + buf * 12288 + ib), 16, 0, 0);
    }
  };
  auto COMPUTE = [&](int buf) {
#pragma unroll
    for (int kk = 0; kk < 2; ++kk) {
      const int sw = (((kk << 2) + fh) ^ rx) << 3;
      bf16x8 as_[4], ah_[4], bi_[3], bh_[3];
#pragma unroll
      for (int mi = 0; mi < 4; ++mi) {
        as_[mi] = *(const bf16x8*)&AsS[buf][(wr + (mi << 4) + fc) * 64 + sw];
        ah_[mi] = *(const bf16x8*)&AsH[buf][(wr + (mi << 4) + fc) * 64 + sw];
      }
#pragma unroll
      for (int ni = 0; ni < 3; ++ni) {
        bi_[ni] = *(const bf16x8*)&BsI[buf][(wn + (ni << 4) + fc) * 64 + sw];
        bh_[ni] = *(const bf16x8*)&BsH[buf][(wn + (ni << 4) + fc) * 64 + sw];
      }
#pragma unroll
      for (int mi = 0; mi < 4; ++mi)
#pragma unroll
        for (int ni = 0; ni < 3; ++ni) {
          acc_i[mi][ni] = __builtin_amdgcn_mfma_f32_16x16x32_bf16(as_[mi], bi_[ni], acc_i[mi][ni], 0, 0, 0);
          acc_h[mi][ni] = __builtin_amdgcn_mfma_f32_16x16x32_bf16(ah_[mi], bh_[ni], acc_h[mi][ni], 0, 0, 0);
        }
    }
  };

  const int nk = Hsz >> 6;   // 32
  STAGE(0, 0);
  for (int kt = 0; kt < nk - 1; ++kt) {
    STAGE(kt + 1, (kt + 1) & 1);
    asm volatile("s_waitcnt vmcnt(14)" ::: "memory");
    __builtin_amdgcn_s_barrier();
    __builtin_amdgcn_sched_barrier(0);
    COMPUTE(kt & 1);
    asm volatile("s_waitcnt lgkmcnt(0)" ::: "memory");
    __builtin_amdgcn_s_barrier();
  }
  asm volatile("s_waitcnt vmcnt(0)" ::: "memory");
  __builtin_amdgcn_s_barrier();
  __builtin_amdgcn_sched_barrier(0);
  COMPUTE((nk - 1) & 1);

  // epilogue: lane owns unit j (all 3 gates) x 16 rows
  const int j = ((blockIdx.x << 1) + (w & 1)) * 16 + fc;    // [0,2048)
  const float bir = b_ih[j],            bhr = b_hh[j];
  const float biz = b_ih[Hsz + j],      bhz = b_hh[Hsz + j];
  const float bin = b_ih[2 * Hsz + j],  bhn = b_hh[2 * Hsz + j];
#pragma unroll
  for (int mi = 0; mi < 4; ++mi) {
#pragma unroll
    for (int r = 0; r < 4; ++r) {
      const int m = bm0 + wr + (mi << 4) + (fh << 2) + r;
      const float ir = acc_i[mi][0][r] + bir, hr = acc_h[mi][0][r] + bhr;
      const float iz = acc_i[mi][1][r] + biz, hz = acc_h[mi][1][r] + bhz;
      const float in_ = acc_i[mi][2][r] + bin, hn = acc_h[mi][2][r] + bhn;
      const float rg = 1.f / (1.f + expf(-(ir + hr)));
      const float zg = 1.f / (1.f + expf(-(iz + hz)));
      const float ng = tanhf(in_ + rg * hn);
      const float hv = (1.f - zg) * ng + zg * hold[(long)m * (Tsz * Hsz) + j];
      hnew[(long)m * (Tsz * Hsz) + j] = hv;
      hb[m * Hsz + j] = f2bf(hv);
    }
  }
}

// ---------------------------------------------------------------------------
// prior/post GEMM + fused rsample.  Bt column-interleaved: row' =
// (j>>4)*32 + is_lv*16 + (j&15).  z=0: prior, z=1: posterior (writes s_b).
// Grid dim3(8, 2, 2), K=2048.
// ---------------------------------------------------------------------------
__global__ __launch_bounds__(256) void gemm_sample2(
    const short* __restrict__ A0, const short* __restrict__ A1,
    const short* __restrict__ B0, const short* __restrict__ B1,
    const float* __restrict__ bi0, const float* __restrict__ bi1,
    const float* __restrict__ n0, const float* __restrict__ n1,
    float* __restrict__ out, short* __restrict__ sb, int t) {
  const int z = blockIdx.z;
  const short* __restrict__ A = z ? A1 : A0;
  const short* __restrict__ Bt = z ? B1 : B0;
  const float* __restrict__ bias = z ? bi1 : bi0;
  const float* __restrict__ noise = z ? n1 : n0;
  const long oS = z ? OUT_QS : OUT_PS, oM = z ? OUT_QM : OUT_PM, oLV = z ? OUT_QLV : OUT_PLV;

  __shared__ __align__(16) short As[2][8192];
  __shared__ __align__(16) short Bs[2][8192];
  const int tid = threadIdx.x;
  const int w = tid >> 6, l = tid & 63;
  const int bm0 = blockIdx.y << 7, bn0 = blockIdx.x << 7;
  const int fc = l & 15, fh = l >> 4;
  const int wr = (w >> 1) << 6, wc = (w & 1) << 6;
  const int rx = fc & 7;
  const int srccol = ((l & 7) ^ ((l >> 3) & 7)) << 3;
  long aoff[4], boff[4];
#pragma unroll
  for (int i = 0; i < 4; ++i) {
    const int row = (((i << 2) + w) << 3) + (l >> 3);
    aoff[i] = (long)(bm0 + row) * Hsz + srccol;
    boff[i] = (long)(bn0 + row) * Hsz + srccol;
  }
  f32x4 acc[4][4];
#pragma unroll
  for (int i = 0; i < 4; ++i)
#pragma unroll
    for (int j = 0; j < 4; ++j) acc[i][j] = f32x4{0.f, 0.f, 0.f, 0.f};

  auto STAGE = [&](int kt, int buf) {
#pragma unroll
    for (int i = 0; i < 4; ++i) {
      const int ib = ((i << 2) + w) << 10;
      __builtin_amdgcn_global_load_lds(
          (const __attribute__((address_space(1))) void*)(A + aoff[i] + (kt << 6)),
          (__attribute__((address_space(3))) void*)((char*)&As[buf][0] + ib), 16, 0, 0);
      __builtin_amdgcn_global_load_lds(
          (const __attribute__((address_space(1))) void*)(Bt + boff[i] + (kt << 6)),
          (__attribute__((address_space(3))) void*)((char*)&Bs[buf][0] + ib), 16, 0, 0);
    }
  };
  auto COMPUTE = [&](int buf) {
#pragma unroll
    for (int kk = 0; kk < 2; ++kk) {
      bf16x8 af[4], bb[4];
#pragma unroll
      for (int mi = 0; mi < 4; ++mi)
        af[mi] = *(const bf16x8*)&As[buf][(wr + (mi << 4) + fc) * 64 + ((((kk << 2) + fh) ^ rx) << 3)];
#pragma unroll
      for (int ni = 0; ni < 4; ++ni)
        bb[ni] = *(const bf16x8*)&Bs[buf][(wc + (ni << 4) + fc) * 64 + ((((kk << 2) + fh) ^ rx) << 3)];
#pragma unroll
      for (int mi = 0; mi < 4; ++mi)
#pragma unroll
        for (int ni = 0; ni < 4; ++ni)
          acc[mi][ni] = __builtin_amdgcn_mfma_f32_16x16x32_bf16(af[mi], bb[ni], acc[mi][ni], 0, 0, 0);
    }
  };

  const int nk = Hsz >> 6;
  STAGE(0, 0);
  for (int kt = 0; kt < nk - 1; ++kt) {
    STAGE(kt + 1, (kt + 1) & 1);
    asm volatile("s_waitcnt vmcnt(8)" ::: "memory");
    __builtin_amdgcn_s_barrier();
    __builtin_amdgcn_sched_barrier(0);
    COMPUTE(kt & 1);
    asm volatile("s_waitcnt lgkmcnt(0)" ::: "memory");
    __builtin_amdgcn_s_barrier();
  }
  asm volatile("s_waitcnt vmcnt(0)" ::: "memory");
  __builtin_amdgcn_s_barrier();
  __builtin_amdgcn_sched_barrier(0);
  COMPUTE((nk - 1) & 1);

#pragma unroll
  for (int mi = 0; mi < 4; ++mi) {
#pragma unroll
    for (int nh = 0; nh < 2; ++nh) {
      const int ni = nh << 1;
      const int j = (((bn0 + wc + (ni << 4)) >> 5) << 4) + fc;   // [0,512)
      const float bm = bias[j], blv = bias[512 + j];
#pragma unroll
      for (int r = 0; r < 4; ++r) {
        const int b = bm0 + wr + (mi << 4) + (fh << 2) + r;
        const float mv = acc[mi][ni][r] + bm;
        const float lv = acc[mi][ni + 1][r] + blv;
        const long noff = ((long)b * TM1 + t) * Ssz + j;
        const float sv = mv + (1.f + expf(lv)) * noise[noff];
        out[oS + (long)b * (Tsz * Ssz) + (long)(t + 1) * Ssz + j] = sv;
        out[oM + noff] = mv;
        out[oLV + noff] = lv;
        if (z) sb[b * Ssz + j] = f2bf(sv);
      }
    }
  }
}

// ---------------------------------------------------------------------------
// small kernels
// ---------------------------------------------------------------------------
__global__ void conv_f2b(const float* __restrict__ src, short* __restrict__ dst, long n) {
  long i = ((long)blockIdx.x * 256 + threadIdx.x) * 4;
  const long stride = (long)gridDim.x * 1024;
  for (; i < n; i += stride) {
    float4 v = *(const float4*)(src + i);
    s16x4 o;
    o[0] = f2bf(v.x); o[1] = f2bf(v.y); o[2] = f2bf(v.z); o[3] = f2bf(v.w);
    *(s16x4*)(dst + i) = o;
  }
}

// gate-permuting fp32->bf16 row copy for W_ih/W_hh [6144, 2048]:
// dst row n' = u*48+g*16+jlo  <-  src row g*2048 + u*16 + jlo
__global__ void conv_perm48(const float* __restrict__ src, short* __restrict__ dst) {
  const long e = ((long)blockIdx.x * 256 + threadIdx.x) * 4;   // grid 12288
  const int np = (int)(e >> 11), col = (int)(e & 2047);
  const int u = np / 48, rem = np - u * 48;
  const int g = rem >> 4, jlo = rem & 15;
  const long srow = ((long)g << 11) + u * 16 + jlo;
  float4 v = *(const float4*)&src[srow * 2048 + col];
  s16x4 o;
  o[0] = f2bf(v.x); o[1] = f2bf(v.y); o[2] = f2bf(v.z); o[3] = f2bf(v.w);
  *(s16x4*)&dst[e] = o;
}

// dst[perm(n)][k] = src[(k0+k)*srcld + n]; PERM=1 interleaves mean/logvar
template<int PERM>
__global__ void transp(const float* __restrict__ src, short* __restrict__ dst,
                       int srcld, int k0, int K, int N) {
  __shared__ float t[32][33];
  const int tx = threadIdx.x, ty = threadIdx.y;
  const int kb = blockIdx.y << 5, nb = blockIdx.x << 5;
#pragma unroll
  for (int i = ty; i < 32; i += 8)
    t[i][tx] = src[(long)(k0 + kb + i) * srcld + nb + tx];
  __syncthreads();
#pragma unroll
  for (int i = ty; i < 32; i += 8) {
    int n = nb + i, drow = n;
    if (PERM) { const int j = n & 511, lvb = n >> 9; drow = ((j >> 4) << 5) | (lvb << 4) | (j & 15); }
    dst[(long)drow * K + kb + tx] = f2bf(t[tx][i]);
  }
}

__global__ void init_kernel(const float* __restrict__ ph, const float* __restrict__ ps,
                            float* __restrict__ out, short* __restrict__ hb, short* __restrict__ sb) {
  const int idx = blockIdx.x * 256 + threadIdx.x;
  const int b = idx >> 11, n = idx & 2047;
  const float h = ph[idx];
  out[(long)b * (Tsz * Hsz) + n] = h;
  hb[idx] = f2bf(h);
  if (n < Ssz) {
    const int sidx = b * Ssz + n;
    const float s = ps[sidx];
    out[OUT_PS + (long)b * (Tsz * Ssz) + n] = s;
    out[OUT_QS + (long)b * (Tsz * Ssz) + n] = s;
    sb[sidx] = f2bf(s);
  }
}

static GArg mk(const short* A, int lda, const short* Bt, int ldb, const float* bias,
               const short* Ci, long ldci, float* oF, int ldoF, long pstride,
               short* oB, int ldoB) {
  GArg g; g.A = A; g.Bt = Bt; g.bias = bias; g.Ci = Ci; g.ldci = ldci;
  g.oF = oF; g.oB = oB; g.lda = lda; g.ldb = ldb; g.ldoF = ldoF; g.ldoB = ldoB;
  g.pstride = pstride;
  return g;
}

extern "C" void kernel_launch(void* const* d_in, const int* in_sizes, int n_in,
                              void* d_out, int out_size, void* d_ws, size_t ws_size,
                              hipStream_t stream) {
  const float* prev_hidden = (const float*)d_in[0];
  const float* prev_state  = (const float*)d_in[1];
  const float* actions     = (const float*)d_in[2];
  const float* obs         = (const float*)d_in[3];
  const float* prior_noise = (const float*)d_in[4];
  const float* post_noise  = (const float*)d_in[5];
  const float* W_sa = (const float*)d_in[6];
  const float* b_sa = (const float*)d_in[7];
  const float* W_ih = (const float*)d_in[8];
  const float* W_hh = (const float*)d_in[9];
  const float* b_ih = (const float*)d_in[10];
  const float* b_hh = (const float*)d_in[11];
  const float* W_ha = (const float*)d_in[12];
  const float* b_ha = (const float*)d_in[13];
  const float* W_prior = (const float*)d_in[14];
  const float* b_prior = (const float*)d_in[15];
  const float* W_ho = (const float*)d_in[16];
  const float* b_ho = (const float*)d_in[17];
  const float* W_post = (const float*)d_in[18];
  const float* b_post = (const float*)d_in[19];
  float* out = (float*)d_out;

  char* p = (char*)d_ws;
  auto alloc = [&](size_t bytes) { char* r = p; p += (bytes + 255) & ~(size_t)255; return r; };
  short* Wih_p   = (short*)alloc(3L * Hsz * Hsz * 2);      // gate-permuted
  short* Whh_p   = (short*)alloc(3L * Hsz * Hsz * 2);      // gate-permuted
  short* Wt_sa_s = (short*)alloc((long)Hsz * Ssz * 2);
  short* Wt_sa_a = (short*)alloc((long)Hsz * Asz * 2);
  short* Wt_ha_h = (short*)alloc((long)Hsz * Hsz * 2);
  short* Wt_ha_a = (short*)alloc((long)Hsz * Asz * 2);
  short* Wt_ho_h = (short*)alloc((long)Hsz * Hsz * 2);
  short* Wt_ho_o = (short*)alloc((long)Hsz * Esz * 2);
  short* Wt_pr   = (short*)alloc(2L * Ssz * Hsz * 2);      // mean/lv interleaved
  short* Wt_po   = (short*)alloc(2L * Ssz * Hsz * 2);      // mean/lv interleaved
  short* obs_b   = (short*)alloc((long)Bsz * Tsz * Esz * 2);
  short* act_b   = (short*)alloc((long)Bsz * Tsz * Asz * 2);
  short* a_pre   = (short*)alloc((long)Bsz * Tsz * Hsz * 2);
  short* ha_a    = (short*)alloc((long)Bsz * Tsz * Hsz * 2);
  short* ho_o    = (short*)alloc((long)Bsz * Tsz * Hsz * 2);
  short* s_b     = (short*)alloc((long)Bsz * Ssz * 2);
  short* h_b     = (short*)alloc((long)Bsz * Hsz * 2);
  short* sa_b    = (short*)alloc((long)Bsz * Hsz * 2);
  short* ha_b    = (short*)alloc((long)Bsz * Hsz * 2);
  short* ho_b    = (short*)alloc((long)Bsz * Hsz * 2);
  (void)ws_size; (void)in_sizes; (void)n_in; (void)out_size;

  // ---- setup ----------------------------------------------------------------
  conv_f2b<<<4096, 256, 0, stream>>>(obs,  obs_b, (long)Bsz * Tsz * Esz);
  conv_f2b<<<1024, 256, 0, stream>>>(actions, act_b, (long)Bsz * Tsz * Asz);
  conv_perm48<<<12288, 256, 0, stream>>>(W_ih, Wih_p);
  conv_perm48<<<12288, 256, 0, stream>>>(W_hh, Whh_p);

  dim3 tb(32, 8);
  transp<0><<<dim3(Hsz / 32, Ssz / 32), tb, 0, stream>>>(W_sa, Wt_sa_s, Hsz, 0,   Ssz, Hsz);
  transp<0><<<dim3(Hsz / 32, Asz / 32), tb, 0, stream>>>(W_sa, Wt_sa_a, Hsz, Ssz, Asz, Hsz);
  transp<0><<<dim3(Hsz / 32, Hsz / 32), tb, 0, stream>>>(W_ha, Wt_ha_h, Hsz, 0,   Hsz, Hsz);
  transp<0><<<dim3(Hsz / 32, Asz / 32), tb, 0, stream>>>(W_ha, Wt_ha_a, Hsz, Hsz, Asz, Hsz);
  transp<0><<<dim3(Hsz / 32, Hsz / 32), tb, 0, stream>>>(W_ho, Wt_ho_h, Hsz, 0,   Hsz, Hsz);
  transp<0><<<dim3(Hsz / 32, Esz / 32), tb, 0, stream>>>(W_ho, Wt_ho_o, Hsz, Hsz, Esz, Hsz);
  transp<1><<<dim3(2 * Ssz / 32, Hsz / 32), tb, 0, stream>>>(W_prior, Wt_pr, 2 * Ssz, 0, Hsz, 2 * Ssz);
  transp<1><<<dim3(2 * Ssz / 32, Hsz / 32), tb, 0, stream>>>(W_post,  Wt_po, 2 * Ssz, 0, Hsz, 2 * Ssz);

  init_kernel<<<2048, 256, 0, stream>>>(prev_hidden, prev_state, out, h_b, s_b);

  // t-independent precomputes
  {
    GArg g0 = mk(act_b, Asz, Wt_sa_a, Asz, b_sa, nullptr, 0, nullptr, 0, 0, a_pre, Hsz);
    GArg g1 = mk(act_b, Asz, Wt_ha_a, Asz, b_ha, nullptr, 0, nullptr, 0, 0, ha_a, Hsz);
    gemm_bt<1, 0, 0, 0, 1><<<dim3(Hsz / 128, (Bsz * Tsz) / 128, 2), 256, 0, stream>>>(g0, g1, Asz);
  }
  {
    GArg g0 = mk(obs_b, Esz, Wt_ho_o, Esz, b_ho, nullptr, 0, nullptr, 0, 0, ho_o, Hsz);
    gemm_bt<1, 0, 0, 0, 1><<<dim3(Hsz / 128, (Bsz * Tsz) / 128, 1), 256, 0, stream>>>(g0, g0, Esz);
  }

  // ---- sequential scan: 4 launches / step ----------------------------------
  const long ldPre = (long)Tsz * Hsz;
  for (int t = 0; t < TM1; ++t) {
    // 1) sa = relu(s @ Wsa_s^T + a_pre[t])                 [256,2048] K=512
    {
      GArg g0 = mk(s_b, Ssz, Wt_sa_s, Ssz, nullptr, a_pre + (long)t * Hsz, ldPre,
                   nullptr, 0, 0, sa_b, Hsz);
      gemm_bt<0, 1, 1, 0, 1><<<dim3(16, 2, 1), 256, 0, stream>>>(g0, g0, Ssz);
    }
    // 2) gi+gh GEMMs + GRU fused -> h                      [256,6144] K=2048
    gigh_gru<<<dim3(64, 2, 1), 256, 0, stream>>>(
        sa_b, h_b, Wih_p, Whh_p, b_ih, b_hh,
        out + (long)t * Hsz, out + (long)(t + 1) * Hsz, h_b);
    // 3) ha = relu(h@Wha + ha_a[t]) ; ho = relu(h@Who + ho_o[t])   unsplit
    {
      GArg g0 = mk(h_b, Hsz, Wt_ha_h, Hsz, nullptr, ha_a + (long)t * Hsz, ldPre,
                   nullptr, 0, 0, ha_b, Hsz);
      GArg g1 = mk(h_b, Hsz, Wt_ho_h, Hsz, nullptr, ho_o + (long)t * Hsz, ldPre,
                   nullptr, 0, 0, ho_b, Hsz);
      gemm_bt<0, 1, 1, 0, 1><<<dim3(16, 2, 2), 256, 0, stream>>>(g0, g1, Hsz);
    }
    // 4) prior/post GEMM + fused rsample                   [256,1024] K=2048
    gemm_sample2<<<dim3(8, 2, 2), 256, 0, stream>>>(
        ha_b, ho_b, Wt_pr, Wt_po, b_prior, b_post,
        prior_noise, post_noise, out, s_b, t);
  }
}

// Round 7
// 6571.641 us; speedup vs baseline: 1.7518x; 1.7518x over previous
//
#include <hip/hip_runtime.h>

// ============================================================================
// RSSM (DynamicsModel) on MI355X — round 7.
// Trunk = round-2 exact (6.64 ms proven).  One change: gi+gh+GRU fused kernel,
// register-safe redesign (r6's version spilled: 96 acc VGPRs + 56 frag + 28
// addr ≈ 250+ -> scratch traffic).  v2: 64x96 block tile, wave 32x48, dual
// accs = 48 VGPRs, grid 256 blocks, LDS 80KB, vmcnt(10).  GRU epilogue writes
// h directly (kills gru launch + 50 MB/step fp32 round-trip).  h_b ping-pong
// fixes r6's intra-kernel read/write race.
// ============================================================================

typedef __attribute__((ext_vector_type(8))) short bf16x8;
typedef __attribute__((ext_vector_type(4))) float f32x4;
typedef __attribute__((ext_vector_type(4))) short s16x4;

#define DEVI static __device__ __forceinline__

DEVI float bf2f(short s) { union { float f; unsigned u; } v; v.u = ((unsigned)(unsigned short)s) << 16; return v.f; }
DEVI short f2bf(float f) {
  union { float f; unsigned u; } v; v.f = f;
  unsigned r = v.u + 0x7FFFu + ((v.u >> 16) & 1u);   // RNE
  return (short)(r >> 16);
}

#define Bsz 256
#define Tsz 64
#define Hsz 2048
#define Ssz 512
#define Asz 64
#define Esz 2048
#define TM1 63

#define PSH (256 * 2048)
#define PSS (256 * 1024)

#define OUT_PS  33554432L
#define OUT_QS  41943040L
#define OUT_PM  50331648L
#define OUT_PLV 58589184L
#define OUT_QM  66846720L
#define OUT_QLV 75104256L

struct GArg {
  const short* A; const short* Bt; const float* bias; const short* Ci;
  float* oF; short* oB;
  int lda, ldb, ldoF, ldoB; long ldci, pstride;
};

// ---------------------------------------------------------------------------
// proven bf16 GEMM (round 2): 128x128 tile, BK=64, 2-deep dbuf, XOR-swizzled
// LDS via pre-swizzled source, counted vmcnt(8).
// blockIdx.z: gemm = z&1, kc = z>>1 (split-K chunk).
// ---------------------------------------------------------------------------
template<int HASBIAS, int HASCI, int RELU, int OUTF, int OUTB>
__global__ __launch_bounds__(256) void gemm_bt(GArg g0, GArg g1, int kcK) {
  const int gemm = blockIdx.z & 1, kc = blockIdx.z >> 1;
  const GArg g = gemm ? g1 : g0;
  const short* __restrict__ Ag = g.A + (long)kc * kcK;
  const short* __restrict__ Bg = g.Bt + (long)kc * kcK;
  __shared__ __align__(16) short As[2][8192];
  __shared__ __align__(16) short Bs[2][8192];
  const int tid = threadIdx.x;
  const int w = tid >> 6, l = tid & 63;
  const int bm0 = blockIdx.y << 7, bn0 = blockIdx.x << 7;
  const int fc = l & 15, fh = l >> 4;
  const int wr = (w >> 1) << 6, wc = (w & 1) << 6;
  const int rx = fc & 7;

  const int srccol = ((l & 7) ^ ((l >> 3) & 7)) << 3;
  long aoff[4], boff[4];
#pragma unroll
  for (int i = 0; i < 4; ++i) {
    const int row = (((i << 2) + w) << 3) + (l >> 3);
    aoff[i] = (long)(bm0 + row) * g.lda + srccol;
    boff[i] = (long)(bn0 + row) * g.ldb + srccol;
  }

  f32x4 acc[4][4];
#pragma unroll
  for (int i = 0; i < 4; ++i)
#pragma unroll
    for (int j = 0; j < 4; ++j) acc[i][j] = f32x4{0.f, 0.f, 0.f, 0.f};

  auto STAGE = [&](int kt, int buf) {
#pragma unroll
    for (int i = 0; i < 4; ++i) {
      const int ib = ((i << 2) + w) << 10;
      __builtin_amdgcn_global_load_lds(
          (const __attribute__((address_space(1))) void*)(Ag + aoff[i] + (kt << 6)),
          (__attribute__((address_space(3))) void*)((char*)&As[buf][0] + ib), 16, 0, 0);
      __builtin_amdgcn_global_load_lds(
          (const __attribute__((address_space(1))) void*)(Bg + boff[i] + (kt << 6)),
          (__attribute__((address_space(3))) void*)((char*)&Bs[buf][0] + ib), 16, 0, 0);
    }
  };
  auto COMPUTE = [&](int buf) {
#pragma unroll
    for (int kk = 0; kk < 2; ++kk) {
      bf16x8 af[4], bb[4];
#pragma unroll
      for (int mi = 0; mi < 4; ++mi)
        af[mi] = *(const bf16x8*)&As[buf][(wr + (mi << 4) + fc) * 64 + ((((kk << 2) + fh) ^ rx) << 3)];
#pragma unroll
      for (int ni = 0; ni < 4; ++ni)
        bb[ni] = *(const bf16x8*)&Bs[buf][(wc + (ni << 4) + fc) * 64 + ((((kk << 2) + fh) ^ rx) << 3)];
#pragma unroll
      for (int mi = 0; mi < 4; ++mi)
#pragma unroll
        for (int ni = 0; ni < 4; ++ni)
          acc[mi][ni] = __builtin_amdgcn_mfma_f32_16x16x32_bf16(af[mi], bb[ni], acc[mi][ni], 0, 0, 0);
    }
  };

  const int nk = kcK >> 6;
  STAGE(0, 0);
  for (int kt = 0; kt < nk - 1; ++kt) {
    STAGE(kt + 1, (kt + 1) & 1);
    asm volatile("s_waitcnt vmcnt(8)" ::: "memory");
    __builtin_amdgcn_s_barrier();
    __builtin_amdgcn_sched_barrier(0);
    COMPUTE(kt & 1);
    asm volatile("s_waitcnt lgkmcnt(0)" ::: "memory");
    __builtin_amdgcn_s_barrier();
  }
  asm volatile("s_waitcnt vmcnt(0)" ::: "memory");
  __builtin_amdgcn_s_barrier();
  __builtin_amdgcn_sched_barrier(0);
  COMPUTE((nk - 1) & 1);

  float* oF = OUTF ? (g.oF + (long)kc * g.pstride) : (float*)nullptr;
#pragma unroll
  for (int mi = 0; mi < 4; ++mi) {
#pragma unroll
    for (int ni = 0; ni < 4; ++ni) {
      const int n = bn0 + wc + (ni << 4) + fc;
      float bv = 0.f;
      if (HASBIAS) bv = g.bias[n];
#pragma unroll
      for (int r = 0; r < 4; ++r) {
        const int m = bm0 + wr + (mi << 4) + (fh << 2) + r;
        float v = acc[mi][ni][r] + bv;
        if (HASCI) v += bf2f(g.Ci[(long)m * g.ldci + n]);
        if (RELU) v = fmaxf(v, 0.f);
        if (OUTF) oF[(long)m * g.ldoF + n] = v;
        if (OUTB) g.oB[(long)m * g.ldoB + n] = f2bf(v);
      }
    }
  }
}

// ---------------------------------------------------------------------------
// gi+gh+GRU fused, register-safe.  Weights gate-permuted:
// dst row n' = u*48 + g*16 + jlo  (unit j = u*16+jlo, gate g in {r,z,n}).
// Block tile 64(m) x 96(n'), 4 waves: wave = 32x48 = 2mi x 3ni frags, TWO acc
// sets (gi from sa, gh from h).  acc = 12 f32x4 = 48 VGPR.  LDS 80 KB.
// Grid dim3(64, 4).  Epilogue: GRU -> h fp32 (out slice) + bf16 (hb_out).
// ---------------------------------------------------------------------------
__global__ __launch_bounds__(256) void gigh_gru(
    const short* __restrict__ sa, const short* __restrict__ hb_in,
    const short* __restrict__ Wih, const short* __restrict__ Whh,
    const float* __restrict__ b_ih, const float* __restrict__ b_hh,
    const float* __restrict__ hold, float* __restrict__ hnew,
    short* __restrict__ hb_out) {
  __shared__ __align__(16) short AsS[2][4096];   // 64x64 dbuf (16 KB)
  __shared__ __align__(16) short AsH[2][4096];
  __shared__ __align__(16) short BsI[2][6144];   // 96x64 dbuf (24 KB)
  __shared__ __align__(16) short BsH[2][6144];
  const int tid = threadIdx.x;
  const int w = tid >> 6, l = tid & 63;
  const int bm0 = blockIdx.y << 6;               // 4 x 64 rows
  const int bn0 = blockIdx.x * 96;               // 64 x 96 packed cols
  const int fc = l & 15, fh = l >> 4;
  const int wr = (w >> 1) << 5;                  // {0,32}
  const int wn = (w & 1) * 48;                   // {0,48}
  const int rx = fc & 7;
  const int srccol = ((l & 7) ^ ((l >> 3) & 7)) << 3;

  long aoff[2], boff[3];
#pragma unroll
  for (int i = 0; i < 2; ++i) {
    const int row = (((i << 2) + w) << 3) + (l >> 3);    // 0..63
    aoff[i] = (long)(bm0 + row) * Hsz + srccol;
  }
#pragma unroll
  for (int i = 0; i < 3; ++i) {
    const int row = (((i << 2) + w) << 3) + (l >> 3);    // 0..95
    boff[i] = (long)(bn0 + row) * Hsz + srccol;
  }

  f32x4 acc_i[2][3], acc_h[2][3];
#pragma unroll
  for (int i = 0; i < 2; ++i)
#pragma unroll
    for (int j = 0; j < 3; ++j) { acc_i[i][j] = f32x4{0.f,0.f,0.f,0.f}; acc_h[i][j] = f32x4{0.f,0.f,0.f,0.f}; }

  auto STAGE = [&](int kt, int buf) {
#pragma unroll
    for (int i = 0; i < 2; ++i) {
      const int ib = ((i << 2) + w) << 10;
      __builtin_amdgcn_global_load_lds(
          (const __attribute__((address_space(1))) void*)(sa + aoff[i] + (kt << 6)),
          (__attribute__((address_space(3))) void*)((char*)&AsS[0][0] + (buf << 13) + ib), 16, 0, 0);
      __builtin_amdgcn_global_load_lds(
          (const __attribute__((address_space(1))) void*)(hb_in + aoff[i] + (kt << 6)),
          (__attribute__((address_space(3))) void*)((char*)&AsH[0][0] + (buf << 13) + ib), 16, 0, 0);
    }
#pragma unroll
    for (int i = 0; i < 3; ++i) {
      const int ib = ((i << 2) + w) << 10;
      __builtin_amdgcn_global_load_lds(
          (const __attribute__((address_space(1))) void*)(Wih + boff[i] + (kt << 6)),
          (__attribute__((address_space(3))) void*)((char*)&BsI[0][0] + buf * 12288 + ib), 16, 0, 0);
      __builtin_amdgcn_global_load_lds(
          (const __attribute__((address_space(1))) void*)(Whh + boff[i] + (kt << 6)),
          (__attribute__((address_space(3))) void*)((char*)&BsH[0][0] + buf * 12288 + ib), 16, 0, 0);
    }
  };
  auto COMPUTE = [&](int buf) {
#pragma unroll
    for (int kk = 0; kk < 2; ++kk) {
      const int sw = (((kk << 2) + fh) ^ rx) << 3;
      bf16x8 as_[2], ah_[2], bi_[3], bh_[3];
#pragma unroll
      for (int mi = 0; mi < 2; ++mi) {
        as_[mi] = *(const bf16x8*)&AsS[buf][(wr + (mi << 4) + fc) * 64 + sw];
        ah_[mi] = *(const bf16x8*)&AsH[buf][(wr + (mi << 4) + fc) * 64 + sw];
      }
#pragma unroll
      for (int ni = 0; ni < 3; ++ni) {
        bi_[ni] = *(const bf16x8*)&BsI[buf][(wn + (ni << 4) + fc) * 64 + sw];
        bh_[ni] = *(const bf16x8*)&BsH[buf][(wn + (ni << 4) + fc) * 64 + sw];
      }
#pragma unroll
      for (int mi = 0; mi < 2; ++mi)
#pragma unroll
        for (int ni = 0; ni < 3; ++ni) {
          acc_i[mi][ni] = __builtin_amdgcn_mfma_f32_16x16x32_bf16(as_[mi], bi_[ni], acc_i[mi][ni], 0, 0, 0);
          acc_h[mi][ni] = __builtin_amdgcn_mfma_f32_16x16x32_bf16(ah_[mi], bh_[ni], acc_h[mi][ni], 0, 0, 0);
        }
    }
  };

  const int nk = Hsz >> 6;   // 32
  STAGE(0, 0);
  for (int kt = 0; kt < nk - 1; ++kt) {
    STAGE(kt + 1, (kt + 1) & 1);
    asm volatile("s_waitcnt vmcnt(10)" ::: "memory");
    __builtin_amdgcn_s_barrier();
    __builtin_amdgcn_sched_barrier(0);
    COMPUTE(kt & 1);
    asm volatile("s_waitcnt lgkmcnt(0)" ::: "memory");
    __builtin_amdgcn_s_barrier();
  }
  asm volatile("s_waitcnt vmcnt(0)" ::: "memory");
  __builtin_amdgcn_s_barrier();
  __builtin_amdgcn_sched_barrier(0);
  COMPUTE((nk - 1) & 1);

  // epilogue: lane owns unit j (3 gates = ni 0,1,2) for 2x16-row frags
  const int j = (((int)blockIdx.x << 1) + (w & 1)) * 16 + fc;   // [0,2048)
  const float bir = b_ih[j],            bhr = b_hh[j];
  const float biz = b_ih[Hsz + j],      bhz = b_hh[Hsz + j];
  const float bin = b_ih[2 * Hsz + j],  bhn = b_hh[2 * Hsz + j];
#pragma unroll
  for (int mi = 0; mi < 2; ++mi) {
#pragma unroll
    for (int r = 0; r < 4; ++r) {
      const int m = bm0 + wr + (mi << 4) + (fh << 2) + r;
      const float ir = acc_i[mi][0][r] + bir, hr = acc_h[mi][0][r] + bhr;
      const float iz = acc_i[mi][1][r] + biz, hz = acc_h[mi][1][r] + bhz;
      const float in_ = acc_i[mi][2][r] + bin, hn = acc_h[mi][2][r] + bhn;
      const float rg = 1.f / (1.f + expf(-(ir + hr)));
      const float zg = 1.f / (1.f + expf(-(iz + hz)));
      const float ng = tanhf(in_ + rg * hn);
      const float hv = (1.f - zg) * ng + zg * hold[(long)m * (Tsz * Hsz) + j];
      hnew[(long)m * (Tsz * Hsz) + j] = hv;
      hb_out[m * Hsz + j] = f2bf(hv);
    }
  }
}

// ---------------------------------------------------------------------------
// small kernels
// ---------------------------------------------------------------------------
__global__ void conv_f2b(const float* __restrict__ src, short* __restrict__ dst, long n) {
  long i = ((long)blockIdx.x * 256 + threadIdx.x) * 4;
  const long stride = (long)gridDim.x * 1024;
  for (; i < n; i += stride) {
    float4 v = *(const float4*)(src + i);
    s16x4 o;
    o[0] = f2bf(v.x); o[1] = f2bf(v.y); o[2] = f2bf(v.z); o[3] = f2bf(v.w);
    *(s16x4*)(dst + i) = o;
  }
}

// gate-permuting fp32->bf16 row copy for W_ih/W_hh [6144,2048]:
// dst row u*48+g*16+jlo  <-  src row g*2048 + u*16 + jlo
__global__ void conv_perm48(const float* __restrict__ src, short* __restrict__ dst) {
  const long e = ((long)blockIdx.x * 256 + threadIdx.x) * 4;   // grid 12288
  const int np = (int)(e >> 11), col = (int)(e & 2047);
  const int u = np / 48, rem = np - u * 48;
  const int g = rem >> 4, jlo = rem & 15;
  const long srow = ((long)g << 11) + u * 16 + jlo;
  float4 v = *(const float4*)&src[srow * 2048 + col];
  s16x4 o;
  o[0] = f2bf(v.x); o[1] = f2bf(v.y); o[2] = f2bf(v.z); o[3] = f2bf(v.w);
  *(s16x4*)&dst[e] = o;
}

__global__ void transp(const float* __restrict__ src, short* __restrict__ dst,
                       int srcld, int k0, int K, int N) {
  __shared__ float t[32][33];
  const int tx = threadIdx.x, ty = threadIdx.y;
  const int kb = blockIdx.y << 5, nb = blockIdx.x << 5;
#pragma unroll
  for (int i = ty; i < 32; i += 8)
    t[i][tx] = src[(long)(k0 + kb + i) * srcld + nb + tx];
  __syncthreads();
#pragma unroll
  for (int i = ty; i < 32; i += 8)
    dst[(long)(nb + i) * K + kb + tx] = f2bf(t[tx][i]);
}

__global__ void init_kernel(const float* __restrict__ ph, const float* __restrict__ ps,
                            float* __restrict__ out, short* __restrict__ hb, short* __restrict__ sb) {
  const int idx = blockIdx.x * 256 + threadIdx.x;
  const int b = idx >> 11, n = idx & 2047;
  const float h = ph[idx];
  out[(long)b * (Tsz * Hsz) + n] = h;
  hb[idx] = f2bf(h);
  if (n < Ssz) {
    const int sidx = b * Ssz + n;
    const float s = ps[sidx];
    out[OUT_PS + (long)b * (Tsz * Ssz) + n] = s;
    out[OUT_QS + (long)b * (Tsz * Ssz) + n] = s;
    sb[sidx] = f2bf(s);
  }
}

__global__ void reduce_relu4(const float* __restrict__ p, const short* __restrict__ ciA,
                             const short* __restrict__ ciB, short* __restrict__ oA,
                             short* __restrict__ oB, int t) {
  const int z = blockIdx.y;
  const float* pz = p + (long)z * 4 * PSH;
  const short* ci = z ? ciB : ciA;
  short* o = z ? oB : oA;
  const int i = (blockIdx.x * 256 + threadIdx.x) * 4;
  const int b = i >> 11, n = i & 2047;
  f32x4 v = *(const f32x4*)&pz[i];
  v += *(const f32x4*)&pz[PSH + i];
  v += *(const f32x4*)&pz[2 * PSH + i];
  v += *(const f32x4*)&pz[3 * PSH + i];
  const s16x4 c = *(const s16x4*)&ci[((long)b * Tsz + t) * Hsz + n];
  s16x4 ov;
#pragma unroll
  for (int k = 0; k < 4; ++k) ov[k] = f2bf(fmaxf(v[k] + bf2f(c[k]), 0.f));
  *(s16x4*)&o[i] = ov;
}

__global__ void sample_kernel(const float* __restrict__ pp,
                              const float* __restrict__ bp, const float* __restrict__ bq,
                              const float* __restrict__ pn, const float* __restrict__ qn,
                              float* __restrict__ out, short* __restrict__ sb, int t) {
  const int idx = blockIdx.x * 256 + threadIdx.x;
  const int b = idx >> 9, j = idx & 511;
  const float* pr = pp;
  const float* po = pp + 4L * PSS;
  const long r0 = (long)b * 1024 + j;
  float pm = bp[j], plv = bp[512 + j], qm = bq[j], qlv = bq[512 + j];
#pragma unroll
  for (int k = 0; k < 4; ++k) {
    pm  += pr[k * PSS + r0];  plv += pr[k * PSS + r0 + 512];
    qm  += po[k * PSS + r0];  qlv += po[k * PSS + r0 + 512];
  }
  const long noff = ((long)b * TM1 + t) * Ssz + j;
  const float psv = pm + (1.f + expf(plv)) * pn[noff];
  const float qsv = qm + (1.f + expf(qlv)) * qn[noff];
  out[OUT_PS + (long)b * (Tsz * Ssz) + (long)(t + 1) * Ssz + j] = psv;
  out[OUT_QS + (long)b * (Tsz * Ssz) + (long)(t + 1) * Ssz + j] = qsv;
  out[OUT_PM  + noff] = pm;
  out[OUT_PLV + noff] = plv;
  out[OUT_QM  + noff] = qm;
  out[OUT_QLV + noff] = qlv;
  sb[idx] = f2bf(qsv);
}

static GArg mk(const short* A, int lda, const short* Bt, int ldb, const float* bias,
               const short* Ci, long ldci, float* oF, int ldoF, long pstride,
               short* oB, int ldoB) {
  GArg g; g.A = A; g.Bt = Bt; g.bias = bias; g.Ci = Ci; g.ldci = ldci;
  g.oF = oF; g.oB = oB; g.lda = lda; g.ldb = ldb; g.ldoF = ldoF; g.ldoB = ldoB;
  g.pstride = pstride;
  return g;
}

extern "C" void kernel_launch(void* const* d_in, const int* in_sizes, int n_in,
                              void* d_out, int out_size, void* d_ws, size_t ws_size,
                              hipStream_t stream) {
  const float* prev_hidden = (const float*)d_in[0];
  const float* prev_state  = (const float*)d_in[1];
  const float* actions     = (const float*)d_in[2];
  const float* obs         = (const float*)d_in[3];
  const float* prior_noise = (const float*)d_in[4];
  const float* post_noise  = (const float*)d_in[5];
  const float* W_sa = (const float*)d_in[6];
  const float* b_sa = (const float*)d_in[7];
  const float* W_ih = (const float*)d_in[8];
  const float* W_hh = (const float*)d_in[9];
  const float* b_ih = (const float*)d_in[10];
  const float* b_hh = (const float*)d_in[11];
  const float* W_ha = (const float*)d_in[12];
  const float* b_ha = (const float*)d_in[13];
  const float* W_prior = (const float*)d_in[14];
  const float* b_prior = (const float*)d_in[15];
  const float* W_ho = (const float*)d_in[16];
  const float* b_ho = (const float*)d_in[17];
  const float* W_post = (const float*)d_in[18];
  const float* b_post = (const float*)d_in[19];
  float* out = (float*)d_out;

  char* p = (char*)d_ws;
  auto alloc = [&](size_t bytes) { char* r = p; p += (bytes + 255) & ~(size_t)255; return r; };
  short* Wih_p   = (short*)alloc(3L * Hsz * Hsz * 2);      // gate-permuted
  short* Whh_p   = (short*)alloc(3L * Hsz * Hsz * 2);      // gate-permuted
  short* Wt_sa_s = (short*)alloc((long)Hsz * Ssz * 2);
  short* Wt_sa_a = (short*)alloc((long)Hsz * Asz * 2);
  short* Wt_ha_h = (short*)alloc((long)Hsz * Hsz * 2);
  short* Wt_ha_a = (short*)alloc((long)Hsz * Asz * 2);
  short* Wt_ho_h = (short*)alloc((long)Hsz * Hsz * 2);
  short* Wt_ho_o = (short*)alloc((long)Hsz * Esz * 2);
  short* Wt_pr   = (short*)alloc(2L * Ssz * Hsz * 2);
  short* Wt_po   = (short*)alloc(2L * Ssz * Hsz * 2);
  short* obs_b   = (short*)alloc((long)Bsz * Tsz * Esz * 2);   // 64 MB, aliased below
  short* act_b   = (short*)alloc((long)Bsz * Tsz * Asz * 2);
  short* a_pre   = (short*)alloc((long)Bsz * Tsz * Hsz * 2);
  short* ha_a    = (short*)alloc((long)Bsz * Tsz * Hsz * 2);
  short* ho_o    = (short*)alloc((long)Bsz * Tsz * Hsz * 2);
  short* s_b     = (short*)alloc((long)Bsz * Ssz * 2);
  short* h_b1    = (short*)alloc((long)Bsz * Hsz * 2);     // h ping-pong
  short* h_b2    = (short*)alloc((long)Bsz * Hsz * 2);
  short* sa_b    = (short*)alloc((long)Bsz * Hsz * 2);
  short* ha_b    = (short*)alloc((long)Bsz * Hsz * 2);
  short* ho_b    = (short*)alloc((long)Bsz * Hsz * 2);
  char* q = (char*)obs_b;                     // alias region (dead after precompute)
  auto alias = [&](size_t bytes) { char* r = q; q += (bytes + 255) & ~(size_t)255; return r; };
  float* haho_p  = (float*)alias(8L * PSH * 4);
  float* prpo_p  = (float*)alias(8L * PSS * 4);
  (void)ws_size; (void)in_sizes; (void)n_in; (void)out_size;

  // ---- setup ----------------------------------------------------------------
  conv_f2b<<<4096, 256, 0, stream>>>(obs,  obs_b, (long)Bsz * Tsz * Esz);
  conv_f2b<<<1024, 256, 0, stream>>>(actions, act_b, (long)Bsz * Tsz * Asz);
  conv_perm48<<<12288, 256, 0, stream>>>(W_ih, Wih_p);
  conv_perm48<<<12288, 256, 0, stream>>>(W_hh, Whh_p);

  dim3 tb(32, 8);
  transp<<<dim3(Hsz / 32, Ssz / 32), tb, 0, stream>>>(W_sa, Wt_sa_s, Hsz, 0,   Ssz, Hsz);
  transp<<<dim3(Hsz / 32, Asz / 32), tb, 0, stream>>>(W_sa, Wt_sa_a, Hsz, Ssz, Asz, Hsz);
  transp<<<dim3(Hsz / 32, Hsz / 32), tb, 0, stream>>>(W_ha, Wt_ha_h, Hsz, 0,   Hsz, Hsz);
  transp<<<dim3(Hsz / 32, Asz / 32), tb, 0, stream>>>(W_ha, Wt_ha_a, Hsz, Hsz, Asz, Hsz);
  transp<<<dim3(Hsz / 32, Hsz / 32), tb, 0, stream>>>(W_ho, Wt_ho_h, Hsz, 0,   Hsz, Hsz);
  transp<<<dim3(Hsz / 32, Esz / 32), tb, 0, stream>>>(W_ho, Wt_ho_o, Hsz, Hsz, Esz, Hsz);
  transp<<<dim3(2 * Ssz / 32, Hsz / 32), tb, 0, stream>>>(W_prior, Wt_pr, 2 * Ssz, 0, Hsz, 2 * Ssz);
  transp<<<dim3(2 * Ssz / 32, Hsz / 32), tb, 0, stream>>>(W_post,  Wt_po, 2 * Ssz, 0, Hsz, 2 * Ssz);

  init_kernel<<<2048, 256, 0, stream>>>(prev_hidden, prev_state, out, h_b1, s_b);

  // t-independent precomputes (before scan: scan aliases obs_b region)
  {
    GArg g0 = mk(act_b, Asz, Wt_sa_a, Asz, b_sa, nullptr, 0, nullptr, 0, 0, a_pre, Hsz);
    GArg g1 = mk(act_b, Asz, Wt_ha_a, Asz, b_ha, nullptr, 0, nullptr, 0, 0, ha_a, Hsz);
    gemm_bt<1, 0, 0, 0, 1><<<dim3(Hsz / 128, (Bsz * Tsz) / 128, 2), 256, 0, stream>>>(g0, g1, Asz);
  }
  {
    GArg g0 = mk(obs_b, Esz, Wt_ho_o, Esz, b_ho, nullptr, 0, nullptr, 0, 0, ho_o, Hsz);
    gemm_bt<1, 0, 0, 0, 1><<<dim3(Hsz / 128, (Bsz * Tsz) / 128, 1), 256, 0, stream>>>(g0, g0, Esz);
  }

  // ---- sequential scan: 6 launches / step -----------------------------------
  const long ldPre = (long)Tsz * Hsz;
  for (int t = 0; t < TM1; ++t) {
    short* hp = (t & 1) ? h_b2 : h_b1;    // h_t (bf16)
    short* hn = (t & 1) ? h_b1 : h_b2;    // h_{t+1} (bf16)
    // 1) sa = relu(s @ Wsa_s^T + a_pre[t])                 [256,2048] K=512
    {
      GArg g0 = mk(s_b, Ssz, Wt_sa_s, Ssz, nullptr, a_pre + (long)t * Hsz, ldPre,
                   nullptr, 0, 0, sa_b, Hsz);
      gemm_bt<0, 1, 1, 0, 1><<<dim3(16, 2, 1), 256, 0, stream>>>(g0, g0, Ssz);
    }
    // 2) gi+gh GEMMs + GRU fused -> h                      [256,6144] K=2048
    gigh_gru<<<dim3(64, 4, 1), 256, 0, stream>>>(
        sa_b, hp, Wih_p, Whh_p, b_ih, b_hh,
        out + (long)t * Hsz, out + (long)(t + 1) * Hsz, hn);
    // 3) ha/ho partials, split-K=4                         [256,2048] K=2048
    {
      GArg g0 = mk(hn, Hsz, Wt_ha_h, Hsz, nullptr, nullptr, 0, haho_p, Hsz, PSH, nullptr, 0);
      GArg g1 = mk(hn, Hsz, Wt_ho_h, Hsz, nullptr, nullptr, 0, haho_p + 4L * PSH, Hsz, PSH, nullptr, 0);
      gemm_bt<0, 0, 0, 1, 0><<<dim3(16, 2, 8), 256, 0, stream>>>(g0, g1, Hsz / 4);
    }
    // 4) reduce + relu -> ha_b / ho_b
    reduce_relu4<<<dim3(512, 2), 256, 0, stream>>>(haho_p, ha_a, ho_o, ha_b, ho_b, t);
    // 5) prior/post partials, split-K=4                    [256,1024] K=2048
    {
      GArg g0 = mk(ha_b, Hsz, Wt_pr, Hsz, nullptr, nullptr, 0, prpo_p, 2 * Ssz, PSS, nullptr, 0);
      GArg g1 = mk(ho_b, Hsz, Wt_po, Hsz, nullptr, nullptr, 0, prpo_p + 4L * PSS, 2 * Ssz, PSS, nullptr, 0);
      gemm_bt<0, 0, 0, 1, 0><<<dim3(8, 2, 8), 256, 0, stream>>>(g0, g1, Hsz / 4);
    }
    // 6) reduce + rsample + outputs
    sample_kernel<<<512, 256, 0, stream>>>(prpo_p, b_prior, b_post,
                                           prior_noise, post_noise, out, s_b, t);
  }
}